// Round 1
// 426.467 us; speedup vs baseline: 1.3556x; 1.3556x over previous
//
#include <hip/hip_runtime.h>
#include <math.h>

#define NB   2048
#define DIN  784
#define HN   256
#define NOUT 10
#define OSTR (HN + HN + NOUT)   // 522

// Per-block LDS. sup/tab/scr are 16B-aligned by placement order.
struct Smem {
  float4  sup[4][HN];      // 16 KB: (node, u, parent-logit, 0) per j — packed staging
  double2 tab[65];         // 1040 B: {ln(k/64), 64/k}, k=64..128 (device-built)
  float   scr[4][16 * 20]; // 5 KB fold scratch: row idx (16 rows × 20 cols) — fallback only now
  float   h2o[4][HN];      // 4 KB
  float   h1n[4][HN];      // 4 KB
  float   tmp[4][HN];      // 4 KB nl-init redistribution
  float   yv [4][16];
};

// ---- bitwise replica of numpy's SIMD float32 exp (exact/fallback path) -----
__device__ __forceinline__ float np_expf(float xf) {
  float q = __fmul_rn(xf, 1.442695040888963f);       // x * NPY_LOG2Ef
  q = __fadd_rn(q, 12582912.0f);                     // 0x1.8p23 round-to-even
  q = __fsub_rn(q, 12582912.0f);
  float x = __builtin_fmaf(q, -6.93145752e-1f, xf);  // Cody-Waite high
  x = __builtin_fmaf(q, -1.42860677e-6f, x);         // Cody-Waite low
  float num = __builtin_fmaf(x, 5.082762527590693718096e-04f,
                                6.757896990527504603057e-03f);
  num = __builtin_fmaf(num, x, 5.114512081637298353406e-02f);
  num = __builtin_fmaf(num, x, 2.473615434895520810817e-01f);
  num = __builtin_fmaf(num, x, 7.257664613233124478488e-01f);
  num = __builtin_fmaf(num, x, 9.999999999980870924916e-01f);
  float den = __builtin_fmaf(x, 2.159509375685829852307e-02f,
                                -2.742335390411667452936e-01f);
  den = __builtin_fmaf(den, x, 1.0f);
  float r = __fdiv_rn(num, den);
  int qi = (int)q;
  return __fmul_rn(r, __int_as_float((qi + 127) << 23));
}

// fp64 log1p for e in (0,1]: t=1+e exact; k=rint(64t) in [64,128]; c=k/64 exact;
// s=(t-c)*(64/k), |s|<=1/128 (t-c exact by Sterbenz); ln(1+s) degree-6 Horner
// (truncation <= ~3e-14 rel — round-8 error class, which flipped zero bits).
__device__ __forceinline__ float np_log1pf(float ef, const double2* __restrict__ tab) {
  if (ef < 0x1p-29f) return ef;            // never taken in practice
  double t  = 1.0 + (double)ef;            // exact
  double kd = rint(t * 64.0);              // k in [64, 128]
  int   idx = (int)kd - 64;
  double2 te = tab[idx];                   // {ln(c), 64/k} in one ds_read_b128
  double c  = kd * 0.015625;               // exact
  double s  = (t - c) * te.y;
  double p  = fma(s, -1.0/6.0, 0.2);       // s(1+s(-1/2+s(1/3+s(-1/4+s(1/5 - s/6)))))
  p = fma(p, s, -0.25);
  p = fma(p, s,  1.0/3.0);
  p = fma(p, s, -0.5);
  p = fma(p, s,  1.0);
  p = p * s;                               // ln(1+s)
  return (float)(te.x + p);
}

// sigmoid-CE, numpy op order: (max(l,0) - l*label) + log1p(exp(-|l|))  [exact]
__device__ __forceinline__ float ce32(float l, float label, const double2* __restrict__ tab) {
  float t3 = __fsub_rn(fmaxf(l, 0.0f), __fmul_rn(l, label));
  return __fadd_rn(t3, np_log1pf(np_expf(-fabsf(l)), tab));
}

// Decision u < prob where prob = fl(1 / fl(1+exp(-z))) — divide-free:
// sign of d = fma(u,w,-1) decides except within |d|<1e-5 of the boundary
// (slack 5e-6 >> CR div error 1.5e-8); exact replica fallback there (wave-
// uniform condition, ~never taken).
__device__ __forceinline__ bool decide(float u, float ez) {
  float w = __fadd_rn(1.0f, ez);
  float d = __builtin_fmaf(u, w, -1.0f);
  if (__builtin_expect(fabsf(d) < 1e-5f, 0)) {
    float prob = __fdiv_rn(1.0f, w);
    return u < prob;
  }
  return d < 0.0f;
}

// lane data movement (bitwise-safe)
template<int CTRL> __device__ __forceinline__ float dppx(float v) {
  return __int_as_float(__builtin_amdgcn_mov_dpp(__float_as_int(v), CTRL, 0xF, 0xF, true));
}
__device__ __forceinline__ float rdl(float v, int l) {
  return __int_as_float(__builtin_amdgcn_readlane(__float_as_int(v), l));
}

// numpy pairwise sum over 10 on lanes 0..9 (uniform result)  [exact/fallback]
__device__ __forceinline__ float sum10(float c) {
  float c0 = rdl(c, 0), c1 = rdl(c, 1), c2 = rdl(c, 2), c3 = rdl(c, 3);
  float c4 = rdl(c, 4), c5 = rdl(c, 5), c6 = rdl(c, 6), c7 = rdl(c, 7);
  float c8 = rdl(c, 8), c9 = rdl(c, 9);
  float t = __fadd_rn(__fadd_rn(__fadd_rn(c0, c1), __fadd_rn(c2, c3)),
                      __fadd_rn(__fadd_rn(c4, c5), __fadd_rn(c6, c7)));
  t = __fadd_rn(t, c8);
  t = __fadd_rn(t, c9);
  return t;
}

// numpy pairwise sum over 256 children (4/lane) via LDS scratch transpose.
// [exact — now only used for init and the rare near-boundary fallback]
__device__ __forceinline__ float fold256_lds(const float c[4], float* __restrict__ scrw,
                                             int idx, int g) {
  *reinterpret_cast<float4*>(scrw + idx * 20 + 4 * g) = make_float4(c[0], c[1], c[2], c[3]);
  const float4* rp = reinterpret_cast<const float4*>(scrw + idx * 20);
  float4 q0 = rp[0], q1 = rp[1], q2 = rp[2], q3 = rp[3];
  float r = q0.x;
  r = __fadd_rn(r, q0.y); r = __fadd_rn(r, q0.z); r = __fadd_rn(r, q0.w);
  r = __fadd_rn(r, q1.x); r = __fadd_rn(r, q1.y); r = __fadd_rn(r, q1.z); r = __fadd_rn(r, q1.w);
  r = __fadd_rn(r, q2.x); r = __fadd_rn(r, q2.y); r = __fadd_rn(r, q2.z); r = __fadd_rn(r, q2.w);
  r = __fadd_rn(r, q3.x); r = __fadd_rn(r, q3.y); r = __fadd_rn(r, q3.z); r = __fadd_rn(r, q3.w);
  r = __fadd_rn(r, dppx<0xB1>(r));      // xor 1 (quad_perm [1,0,3,2])
  r = __fadd_rn(r, dppx<0x4E>(r));      // xor 2 (quad_perm [2,3,0,1])
  float B0 = rdl(r, 0), B1 = rdl(r, 4), B2 = rdl(r, 8), B3 = rdl(r, 12);
  return __fadd_rn(__fadd_rn(B0, B1), __fadd_rn(B2, B3));
}

// ---- FAST path helpers ------------------------------------------------------
// fast CE: hardware transcendentals. abs error vs ce32 <= ~2.5e-7 per child.
__device__ __forceinline__ float fast_ce(float l, float label) {
  float t3 = __fsub_rn(fmaxf(l, 0.0f), __fmul_rn(l, label));
  float e  = __expf(-fabsf(l));
  return t3 + __logf(1.0f + e);
}

// fast 256-sum: xor-butterfly (each stage pairs L with L^k and adds the SAME
// two values on both lanes — commutative fadd => bit-identical across lanes,
// so the result is wave-uniform; required so the decision stays uniform).
// No LDS data round-trip (swizzle is conflict-free lane exchange).
__device__ __forceinline__ float fast_sum256(const float c[4]) {
  float r = (c[0] + c[1]) + (c[2] + c[3]);
  r = r + dppx<0xB1>(r);                  // ^1
  r = r + dppx<0x4E>(r);                  // ^2
  r = r + __int_as_float(__builtin_amdgcn_ds_swizzle(__float_as_int(r), 0x101F)); // ^4
  r = r + dppx<0x128>(r);                 // row_ror:8 pairs L<->L^8 within 16-row
  return (rdl(r, 0) + rdl(r, 16)) + (rdl(r, 32) + rdl(r, 48));
}

// Guard band: |d_fast - d_exact| <= u*e*(~2.6e-4) + ~1e-6  (fast-sum order
// error + hw exp/log ulp). Threshold u*e*0.05 + 1e-4 gives >=100x margin and
// strictly contains the reference's own |d|<1e-5 div-replica region.
// Written as !(|d| >= thr) so a NaN d (u==0 & e==inf) also takes the exact path.
__device__ __forceinline__ bool need_exact(float d, float mm) {
  return !(fabsf(d) >= __builtin_fmaf(mm, 0.05f, 1e-4f));
}

__global__ __launch_bounds__(256) void stoch_mlp(
    const float* __restrict__ x,  const int* __restrict__ h1,
    const int* __restrict__ h2,   const int* __restrict__ y,
    const float* __restrict__ W1, const float* __restrict__ b1,
    const float* __restrict__ W2, const float* __restrict__ b2,
    const float* __restrict__ Wo, const float* __restrict__ bo,
    const float* __restrict__ u1, const float* __restrict__ u2,
    float* __restrict__ out)
{
  __shared__ Smem sm;
  const int t    = threadIdx.x;
  const int lane = t & 63;
  const int wid  = t >> 6;            // wave id == local batch row
  const int b0   = blockIdx.x * 4;
  const int b    = b0 + wid;

  // ---- phase 1: tables, states, pl1 = x@W1 (BLAS fp32) + packed staging ---
  if (t < 65) {
    double c = (double)(t + 64) * 0.015625;
    sm.tab[t] = make_double2(log(c), 64.0 / (double)(t + 64));
  }
  for (int j = lane; j < HN; j += 64) sm.h2o[wid][j] = (float)h2[b * HN + j];
  if (lane < 16) sm.yv[wid][lane] = (lane < NOUT) ? (float)y[b * NOUT + lane] : 0.0f;
  {
    float a0 = 0.0f, a1 = 0.0f, a2 = 0.0f, a3 = 0.0f;   // sequential-k FMA chains
    const float* x0 = x + (size_t)b0 * DIN;
    for (int k = 0; k < DIN; ++k) {
      float wk = W1[k * HN + t];
      a0 = __builtin_fmaf(x0[k],           wk, a0);
      a1 = __builtin_fmaf(x0[DIN   + k],   wk, a1);
      a2 = __builtin_fmaf(x0[2*DIN + k],   wk, a2);
      a3 = __builtin_fmaf(x0[3*DIN + k],   wk, a3);
    }
    float bb = b1[t];
    float4 uv = *reinterpret_cast<const float4*>(u1 + (size_t)t * NB + b0);
    float n0 = (float)h1[(b0 + 0) * HN + t];
    float n1 = (float)h1[(b0 + 1) * HN + t];
    float n2 = (float)h1[(b0 + 2) * HN + t];
    float n3 = (float)h1[(b0 + 3) * HN + t];
    sm.sup[0][t] = make_float4(n0, uv.x, __fadd_rn(a0, bb), 0.0f);
    sm.sup[1][t] = make_float4(n1, uv.y, __fadd_rn(a1, bb), 0.0f);
    sm.sup[2][t] = make_float4(n2, uv.z, __fadd_rn(a2, bb), 0.0f);
    sm.sup[3][t] = make_float4(n3, uv.w, __fadd_rn(a3, bb), 0.0f);
  }
  __syncthreads();   // sup + tab written cross-wave

  const double2* tab = sm.tab;
  float* scrw = &sm.scr[wid][0];

  // nl-init = h1_old @ W2 + b2 (masked fp32 == BLAS chain)
  {
    float acc[4] = {0.0f, 0.0f, 0.0f, 0.0f};
    for (int j = 0; j < HN; ++j) {
      if (sm.sup[wid][j].x != 0.0f) {
        float4 wf = *reinterpret_cast<const float4*>(W2 + (size_t)j * HN + 4*lane);
        acc[0] = __fadd_rn(acc[0], wf.x);  acc[1] = __fadd_rn(acc[1], wf.y);
        acc[2] = __fadd_rn(acc[2], wf.z);  acc[3] = __fadd_rn(acc[3], wf.w);
      }
    }
    float4 bv = *reinterpret_cast<const float4*>(b2 + 4*lane);
    *reinterpret_cast<float4*>(&sm.tmp[wid][4*lane]) =
        make_float4(__fadd_rn(acc[0], bv.x), __fadd_rn(acc[1], bv.y),
                    __fadd_rn(acc[2], bv.z), __fadd_rn(acc[3], bv.w));
  }
  // tmp is wave-private; same-wave DS ordering -> no barrier

  // ---- phase 2: layer-0 scan — 4 children per lane ------------------------
  const int idx  = lane & 15;
  const int g    = lane >> 4;
  const int half = idx >> 3;
  const int jacc = idx & 7;
  const int kb   = half * 128 + (4 * g) * 8 + jacc;   // + i*8

  float nlv[4], nv[4], wv[4];
  #pragma unroll
  for (int i = 0; i < 4; ++i) {
    int k = kb + i * 8;
    nlv[i] = sm.tmp[wid][k];
    nv[i]  = sm.h2o[wid][k];
    wv[i]  = W2[k];                    // row 0
  }
  float S_c;                           // carried CE sum (fast estimate between fallbacks)
  {
    float ci[4];                       // exact init (once, cheap): tightens invariant
    #pragma unroll
    for (int i = 0; i < 4; ++i) ci[i] = ce32(nlv[i], nv[i], tab);
    S_c = fold256_lds(ci, scrw, idx, g);
  }

  {
    float4 supC = sm.sup[wid][0];
    for (int j = 0; j < HN; ++j) {
      float node = supC.x, uj = supC.y, plj = supC.z;
      bool  nd   = (node != 0.0f);
      int   jn   = (j + 1) & (HN - 1);           // branchless wrapped prefetch
      float4 supN = sm.sup[wid][jn];
      float wcur[4];
      #pragma unroll
      for (int i = 0; i < 4; ++i) wcur[i] = wv[i];
      #pragma unroll
      for (int i = 0; i < 4; ++i) wv[i] = W2[(size_t)jn * HN + kb + i * 8];
      float one_m = __fsub_rn(1.0f, node);
      float nl0[4], nl1[4], chg[4];
      #pragma unroll
      for (int i = 0; i < 4; ++i) {
        nl0[i] = __fsub_rn(nlv[i], __fmul_rn(node,  wcur[i]));
        nl1[i] = __fadd_rn(nlv[i], __fmul_rn(one_m, wcur[i]));
        chg[i] = fast_ce(nd ? nl0[i] : nl1[i], nv[i]);   // fresh side, FAST
      }
      float F  = fast_sum256(chg);                // wave-uniform fast sum
      float S0 = nd ? F : S_c;
      float S1 = nd ? S_c : F;
      float z  = __fsub_rn(__fadd_rn(plj, -S1), -S0);
      float ez = __expf(-z);
      float d  = __builtin_fmaf(uj, 1.0f + ez, -1.0f);
      float mm = uj * ez;
      bool nw;
      if (__builtin_expect(need_exact(d, mm), 0)) {
        // near-boundary: recompute BOTH sides with the bitwise numpy replica
        float c0i[4], c1i[4];
        #pragma unroll
        for (int i = 0; i < 4; ++i) {
          c0i[i] = ce32(nl0[i], nv[i], tab);
          c1i[i] = ce32(nl1[i], nv[i], tab);
        }
        float S0e = fold256_lds(c0i, scrw, idx, g);
        float S1e = fold256_lds(c1i, scrw, idx, g);
        float ze  = __fsub_rn(__fadd_rn(plj, -S1e), -S0e);
        nw  = decide(uj, np_expf(-ze));
        S_c = nw ? S1e : S0e;                     // re-anchor carry to exact
      } else {
        nw  = d < 0.0f;                           // provably == reference decision
        S_c = (nw != nd) ? F : S_c;
      }
      #pragma unroll
      for (int i = 0; i < 4; ++i) nlv[i] = nw ? nl1[i] : nl0[i];   // exact fp32 update
      if (lane == 0) sm.h1n[wid][j] = nw ? 1.0f : 0.0f;
      supC = supN;
    }
  }
  // h1n wave-private; no barrier needed

  // ---- phase 3: pl2 = h1_new @ W2 + b2 (masked fp32); repack staging ------
  {
    float acc[4] = {0.0f, 0.0f, 0.0f, 0.0f};
    for (int j = 0; j < HN; ++j) {
      if (sm.h1n[wid][j] != 0.0f) {
        float4 wf = *reinterpret_cast<const float4*>(W2 + (size_t)j * HN + 4*lane);
        acc[0] = __fadd_rn(acc[0], wf.x);  acc[1] = __fadd_rn(acc[1], wf.y);
        acc[2] = __fadd_rn(acc[2], wf.z);  acc[3] = __fadd_rn(acc[3], wf.w);
      }
    }
    float4 bv = *reinterpret_cast<const float4*>(b2 + 4*lane);
    float p2[4] = {__fadd_rn(acc[0], bv.x), __fadd_rn(acc[1], bv.y),
                   __fadd_rn(acc[2], bv.z), __fadd_rn(acc[3], bv.w)};
    #pragma unroll
    for (int i = 0; i < 4; ++i) {
      int j = 4 * lane + i;
      sm.sup[wid][j] = make_float4(sm.h2o[wid][j], u2[(size_t)j * NB + b], p2[i], 0.0f);
    }
  }

  // layer-1 init: nlo = h2_old @ Wout + bout (masked fp32); nvy = y
  float nvy = 0.0f, nlo = 0.0f;
  if (lane < NOUT) {
    nvy = sm.yv[wid][lane];
    float a = 0.0f;
    for (int j = 0; j < HN; ++j)
      if (sm.h2o[wid][j] != 0.0f) a = __fadd_rn(a, Wo[j * NOUT + lane]);
    nlo = __fadd_rn(a, bo[lane]);
  }
  float S_c1 = sum10((lane < NOUT) ? ce32(nlo, nvy, tab) : 0.0f);   // exact init

  // ---- phase 4: layer-1 scan (10 children on lanes 0..9) ------------------
  {
    float w = (lane < NOUT) ? Wo[lane] : 0.0f;
    float4 supC = sm.sup[wid][0];
    for (int j = 0; j < HN; ++j) {
      float node = supC.x, uj = supC.y, plj = supC.z;
      bool  nd   = (node != 0.0f);
      int   jn   = (j + 1) & (HN - 1);
      float4 supN = sm.sup[wid][jn];
      float wnn = (lane < NOUT) ? Wo[jn * NOUT + lane] : 0.0f;
      float one_m = __fsub_rn(1.0f, node);
      float nl0 = __fsub_rn(nlo, __fmul_rn(node,  w));
      float nl1 = __fadd_rn(nlo, __fmul_rn(one_m, w));
      float chg = (lane < NOUT) ? fast_ce(nd ? nl0 : nl1, nvy) : 0.0f;
      // fast 10-sum: quad butterflies (bit-uniform) then SGPR-broadcast tail
      float r = chg;
      r = r + dppx<0xB1>(r);
      r = r + dppx<0x4E>(r);
      float F  = (rdl(r, 0) + rdl(r, 4)) + rdl(r, 8);   // lanes 10..15 hold 0
      float S0 = nd ? F : S_c1;
      float S1 = nd ? S_c1 : F;
      float z  = __fsub_rn(__fadd_rn(plj, -S1), -S0);
      float ez = __expf(-z);
      float d  = __builtin_fmaf(uj, 1.0f + ez, -1.0f);
      float mm = uj * ez;
      bool nw;
      if (__builtin_expect(need_exact(d, mm), 0)) {
        float c0 = (lane < NOUT) ? ce32(nl0, nvy, tab) : 0.0f;
        float c1 = (lane < NOUT) ? ce32(nl1, nvy, tab) : 0.0f;
        float S0e = sum10(c0);
        float S1e = sum10(c1);
        float ze  = __fsub_rn(__fadd_rn(plj, -S1e), -S0e);
        nw   = decide(uj, np_expf(-ze));
        S_c1 = nw ? S1e : S0e;
      } else {
        nw   = d < 0.0f;
        S_c1 = (nw != nd) ? F : S_c1;
      }
      nlo  = nw ? nl1 : nl0;                       // exact fp32 update
      if (lane == 0) out[(size_t)b * OSTR + HN + j] = nw ? 1.0f : 0.0f;
      supC = supN;
      w = wnn;
    }
  }

  // ---- phase 5: outputs ---------------------------------------------------
  float* orow = out + (size_t)b * OSTR;
  for (int j = lane; j < HN; j += 64) orow[j] = sm.h1n[wid][j];
  if (lane < NOUT) orow[2*HN + lane] = nlo;
}

extern "C" void kernel_launch(void* const* d_in, const int* in_sizes, int n_in,
                              void* d_out, int out_size, void* d_ws, size_t ws_size,
                              hipStream_t stream) {
  const float* x  = (const float*)d_in[0];
  const int*   h1 = (const int*)  d_in[1];
  const int*   h2 = (const int*)  d_in[2];
  const int*   y  = (const int*)  d_in[3];
  const float* W1 = (const float*)d_in[4];
  const float* b1 = (const float*)d_in[5];
  const float* W2 = (const float*)d_in[6];
  const float* b2 = (const float*)d_in[7];
  const float* Wo = (const float*)d_in[8];
  const float* bo = (const float*)d_in[9];
  const float* u1 = (const float*)d_in[10];
  const float* u2 = (const float*)d_in[11];
  stoch_mlp<<<NB/4, 256, 0, stream>>>(x, h1, h2, y, W1, b1, W2, b2, Wo, bo, u1, u2,
                                      (float*)d_out);
}

// Round 2
// 324.481 us; speedup vs baseline: 1.7816x; 1.3143x over previous
//
#include <hip/hip_runtime.h>
#include <math.h>

#define NB   2048
#define DIN  784
#define HN   256
#define NOUT 10
#define OSTR (HN + HN + NOUT)   // 522

// Per-block LDS. sup/tab/scr are 16B-aligned by placement order.
struct Smem {
  float4  sup[4][HN];      // 16 KB: (node, u, parent-logit, logit(u) or NaN) per j
  double2 tab[65];         // 1040 B: {ln(k/64), 64/k}, k=64..128 (device-built)
  float   scr[4][16 * 20]; // 5 KB fold scratch (exact init + rare fallback only)
  float   h2o[4][HN];      // 4 KB
  float   h1n[4][HN];      // 4 KB
  float   tmp[4][HN];      // 4 KB nl-init redistribution
  float   yv [4][16];
};

// ---- bitwise replica of numpy's SIMD float32 exp (exact/fallback path) -----
__device__ __forceinline__ float np_expf(float xf) {
  float q = __fmul_rn(xf, 1.442695040888963f);       // x * NPY_LOG2Ef
  q = __fadd_rn(q, 12582912.0f);                     // 0x1.8p23 round-to-even
  q = __fsub_rn(q, 12582912.0f);
  float x = __builtin_fmaf(q, -6.93145752e-1f, xf);  // Cody-Waite high
  x = __builtin_fmaf(q, -1.42860677e-6f, x);         // Cody-Waite low
  float num = __builtin_fmaf(x, 5.082762527590693718096e-04f,
                                6.757896990527504603057e-03f);
  num = __builtin_fmaf(num, x, 5.114512081637298353406e-02f);
  num = __builtin_fmaf(num, x, 2.473615434895520810817e-01f);
  num = __builtin_fmaf(num, x, 7.257664613233124478488e-01f);
  num = __builtin_fmaf(num, x, 9.999999999980870924916e-01f);
  float den = __builtin_fmaf(x, 2.159509375685829852307e-02f,
                                -2.742335390411667452936e-01f);
  den = __builtin_fmaf(den, x, 1.0f);
  float r = __fdiv_rn(num, den);
  int qi = (int)q;
  return __fmul_rn(r, __int_as_float((qi + 127) << 23));
}

// fp64 log1p for e in (0,1] — bitwise replica class (exact/fallback path)
__device__ __forceinline__ float np_log1pf(float ef, const double2* __restrict__ tab) {
  if (ef < 0x1p-29f) return ef;            // never taken in practice
  double t  = 1.0 + (double)ef;            // exact
  double kd = rint(t * 64.0);              // k in [64, 128]
  int   idx = (int)kd - 64;
  double2 te = tab[idx];                   // {ln(c), 64/k} in one ds_read_b128
  double c  = kd * 0.015625;               // exact
  double s  = (t - c) * te.y;
  double p  = fma(s, -1.0/6.0, 0.2);
  p = fma(p, s, -0.25);
  p = fma(p, s,  1.0/3.0);
  p = fma(p, s, -0.5);
  p = fma(p, s,  1.0);
  p = p * s;                               // ln(1+s)
  return (float)(te.x + p);
}

// sigmoid-CE, numpy op order: (max(l,0) - l*label) + log1p(exp(-|l|))  [exact]
__device__ __forceinline__ float ce32(float l, float label, const double2* __restrict__ tab) {
  float t3 = __fsub_rn(fmaxf(l, 0.0f), __fmul_rn(l, label));
  return __fadd_rn(t3, np_log1pf(np_expf(-fabsf(l)), tab));
}

// Exact decision u < prob, prob = fl(1 / fl(1+exp(-z))) — divide-free w/ replica
// fallback within |d|<1e-5 of the boundary.  [exact/fallback path]
__device__ __forceinline__ bool decide(float u, float ez) {
  float w = __fadd_rn(1.0f, ez);
  float d = __builtin_fmaf(u, w, -1.0f);
  if (__builtin_expect(fabsf(d) < 1e-5f, 0)) {
    float prob = __fdiv_rn(1.0f, w);
    return u < prob;
  }
  return d < 0.0f;
}

// lane data movement (bitwise-safe)
template<int CTRL> __device__ __forceinline__ float dppx(float v) {
  return __int_as_float(__builtin_amdgcn_mov_dpp(__float_as_int(v), CTRL, 0xF, 0xF, true));
}
__device__ __forceinline__ float rdl(float v, int l) {
  return __int_as_float(__builtin_amdgcn_readlane(__float_as_int(v), l));
}

// numpy pairwise sum over 10 on lanes 0..9 (uniform result)  [exact/fallback]
__device__ __forceinline__ float sum10(float c) {
  float c0 = rdl(c, 0), c1 = rdl(c, 1), c2 = rdl(c, 2), c3 = rdl(c, 3);
  float c4 = rdl(c, 4), c5 = rdl(c, 5), c6 = rdl(c, 6), c7 = rdl(c, 7);
  float c8 = rdl(c, 8), c9 = rdl(c, 9);
  float t = __fadd_rn(__fadd_rn(__fadd_rn(c0, c1), __fadd_rn(c2, c3)),
                      __fadd_rn(__fadd_rn(c4, c5), __fadd_rn(c6, c7)));
  t = __fadd_rn(t, c8);
  t = __fadd_rn(t, c9);
  return t;
}

// numpy pairwise sum over 256 children (4/lane) via LDS scratch transpose.
// [exact — only used for init and the rare near-boundary fallback]
__device__ __forceinline__ float fold256_lds(const float c[4], float* __restrict__ scrw,
                                             int idx, int g) {
  *reinterpret_cast<float4*>(scrw + idx * 20 + 4 * g) = make_float4(c[0], c[1], c[2], c[3]);
  const float4* rp = reinterpret_cast<const float4*>(scrw + idx * 20);
  float4 q0 = rp[0], q1 = rp[1], q2 = rp[2], q3 = rp[3];
  float r = q0.x;
  r = __fadd_rn(r, q0.y); r = __fadd_rn(r, q0.z); r = __fadd_rn(r, q0.w);
  r = __fadd_rn(r, q1.x); r = __fadd_rn(r, q1.y); r = __fadd_rn(r, q1.z); r = __fadd_rn(r, q1.w);
  r = __fadd_rn(r, q2.x); r = __fadd_rn(r, q2.y); r = __fadd_rn(r, q2.z); r = __fadd_rn(r, q2.w);
  r = __fadd_rn(r, q3.x); r = __fadd_rn(r, q3.y); r = __fadd_rn(r, q3.z); r = __fadd_rn(r, q3.w);
  r = __fadd_rn(r, dppx<0xB1>(r));      // xor 1 (quad_perm [1,0,3,2])
  r = __fadd_rn(r, dppx<0x4E>(r));      // xor 2 (quad_perm [2,3,0,1])
  float B0 = rdl(r, 0), B1 = rdl(r, 4), B2 = rdl(r, 8), B3 = rdl(r, 12);
  return __fadd_rn(__fadd_rn(B0, B1), __fadd_rn(B2, B3));
}

// ---- FAST path helpers ------------------------------------------------------
// fast 256-sum, all-DPP (no LDS wait): quad ^1, ^2, then row_ror:4, row_ror:8
// give every lane its 16-lane-row sum (rotation orders differ per lane but each
// is a deterministic full sum — error bound covers any order). readlane tail
// makes F wave-uniform, which keeps the decision branch wave-uniform.
__device__ __forceinline__ float fast_sum256(float loc) {
  float r = loc;
  r = r + dppx<0xB1>(r);                  // quad xor 1
  r = r + dppx<0x4E>(r);                  // quad xor 2
  r = r + dppx<0x124>(r);                 // row_ror:4
  r = r + dppx<0x128>(r);                 // row_ror:8
  return (rdl(r, 0) + rdl(r, 16)) + (rdl(r, 32) + rdl(r, 48));
}

// Precomputed decision threshold in z-space: u < sigmoid_fl(z)  <=>  z > lu,
// valid outside a |z-lu| < 0.05 band for u in [1e-4, 0.9999] (fast-sum error
// <=~3e-3 + fl-sigmoid boundary offset <=~2e-3 at the cutoff -> >=10x margin).
// Extreme u -> NaN, which routes !(|d|>=thr) to the exact path.
__device__ __forceinline__ float lu_of(float u) {
  if (u < 1e-4f || u > 0.9999f) return __int_as_float(0x7FC00000);
  return __logf(u) - __logf(__fsub_rn(1.0f, u));
}

#define ZBAND 0.05f
#define LN2F  0.6931471805599453f

__global__ __launch_bounds__(256) void stoch_mlp(
    const float* __restrict__ x,  const int* __restrict__ h1,
    const int* __restrict__ h2,   const int* __restrict__ y,
    const float* __restrict__ W1, const float* __restrict__ b1,
    const float* __restrict__ W2, const float* __restrict__ b2,
    const float* __restrict__ Wo, const float* __restrict__ bo,
    const float* __restrict__ u1, const float* __restrict__ u2,
    float* __restrict__ out)
{
  __shared__ Smem sm;
  const int t    = threadIdx.x;
  const int lane = t & 63;
  const int wid  = t >> 6;            // wave id == local batch row
  const int b0   = blockIdx.x * 4;
  const int b    = b0 + wid;

  // ---- phase 1: tables, states, pl1 = x@W1 (BLAS fp32) + packed staging ---
  if (t < 65) {
    double c = (double)(t + 64) * 0.015625;
    sm.tab[t] = make_double2(log(c), 64.0 / (double)(t + 64));
  }
  for (int j = lane; j < HN; j += 64) sm.h2o[wid][j] = (float)h2[b * HN + j];
  if (lane < 16) sm.yv[wid][lane] = (lane < NOUT) ? (float)y[b * NOUT + lane] : 0.0f;
  {
    float a0 = 0.0f, a1 = 0.0f, a2 = 0.0f, a3 = 0.0f;   // sequential-k FMA chains
    const float* x0 = x + (size_t)b0 * DIN;
    for (int k = 0; k < DIN; ++k) {
      float wk = W1[k * HN + t];
      a0 = __builtin_fmaf(x0[k],           wk, a0);
      a1 = __builtin_fmaf(x0[DIN   + k],   wk, a1);
      a2 = __builtin_fmaf(x0[2*DIN + k],   wk, a2);
      a3 = __builtin_fmaf(x0[3*DIN + k],   wk, a3);
    }
    float bb = b1[t];
    float4 uv = *reinterpret_cast<const float4*>(u1 + (size_t)t * NB + b0);
    float n0 = (float)h1[(b0 + 0) * HN + t];
    float n1 = (float)h1[(b0 + 1) * HN + t];
    float n2 = (float)h1[(b0 + 2) * HN + t];
    float n3 = (float)h1[(b0 + 3) * HN + t];
    sm.sup[0][t] = make_float4(n0, uv.x, __fadd_rn(a0, bb), lu_of(uv.x));
    sm.sup[1][t] = make_float4(n1, uv.y, __fadd_rn(a1, bb), lu_of(uv.y));
    sm.sup[2][t] = make_float4(n2, uv.z, __fadd_rn(a2, bb), lu_of(uv.z));
    sm.sup[3][t] = make_float4(n3, uv.w, __fadd_rn(a3, bb), lu_of(uv.w));
  }
  __syncthreads();   // sup + tab written cross-wave

  const double2* tab = sm.tab;
  float* scrw = &sm.scr[wid][0];

  // nl-init = h1_old @ W2 + b2. Branchless fma(node,w,acc) is bitwise == the
  // masked add chain: fma(1,w,a)=fl(w+a), fma(0,w,a)=a (acc never -0).
  {
    float acc[4] = {0.0f, 0.0f, 0.0f, 0.0f};
    for (int j = 0; j < HN; ++j) {
      float nodej = sm.sup[wid][j].x;
      float4 wf = *reinterpret_cast<const float4*>(W2 + (size_t)j * HN + 4*lane);
      acc[0] = __builtin_fmaf(nodej, wf.x, acc[0]);
      acc[1] = __builtin_fmaf(nodej, wf.y, acc[1]);
      acc[2] = __builtin_fmaf(nodej, wf.z, acc[2]);
      acc[3] = __builtin_fmaf(nodej, wf.w, acc[3]);
    }
    float4 bv = *reinterpret_cast<const float4*>(b2 + 4*lane);
    *reinterpret_cast<float4*>(&sm.tmp[wid][4*lane]) =
        make_float4(__fadd_rn(acc[0], bv.x), __fadd_rn(acc[1], bv.y),
                    __fadd_rn(acc[2], bv.z), __fadd_rn(acc[3], bv.w));
  }
  // tmp is wave-private; same-wave DS ordering -> no barrier

  // ---- phase 2: layer-0 scan — 4 children per lane ------------------------
  const int idx  = lane & 15;
  const int g    = lane >> 4;
  const int half = idx >> 3;
  const int jacc = idx & 7;
  const int kb   = half * 128 + (4 * g) * 8 + jacc;   // + i*8

  float nlv[4], nv[4], wv[4];
  int   smk[4];                        // per-child label sign mask
  #pragma unroll
  for (int i = 0; i < 4; ++i) {
    int k = kb + i * 8;
    nlv[i] = sm.tmp[wid][k];
    nv[i]  = sm.h2o[wid][k];
    smk[i] = (nv[i] != 0.0f) ? (int)0x80000000 : 0;
    wv[i]  = W2[k];                    // row 0
  }
  float S_c;                           // carried CE sum (fast between fallbacks)
  {
    float ci[4];                       // exact init (once): tight anchor
    #pragma unroll
    for (int i = 0; i < 4; ++i) ci[i] = ce32(nlv[i], nv[i], tab);
    S_c = fold256_lds(ci, scrw, idx, g);
  }

  {
    float4 supC = sm.sup[wid][0];
    for (int j = 0; j < HN; ++j) {
      float node = supC.x, uj = supC.y, plj = supC.z, luj = supC.w;
      bool  nd   = (node != 0.0f);
      int   jn   = (j + 1) & (HN - 1);           // branchless wrapped prefetch
      float4 supN = sm.sup[wid][jn];
      float wn[4];
      #pragma unroll
      for (int i = 0; i < 4; ++i) wn[i] = W2[(size_t)jn * HN + kb + i * 8];

      // fresh side only: the stale side is bitwise nlv itself (node in {0,1})
      int ndm = nd ? (int)0x80000000 : 0;
      float fresh[4], t3[4], p[4];
      #pragma unroll
      for (int i = 0; i < 4; ++i) {
        float ws = __int_as_float(__float_as_int(wv[i]) ^ ndm);  // exact +/-w
        fresh[i] = __fadd_rn(nlv[i], ws);        // == fl(nlv -/+ w) bitwise
        float sl = __int_as_float(__float_as_int(fresh[i]) ^ smk[i]);
        t3[i] = fmaxf(sl, 0.0f);                 // == max(l,0)-l*label bitwise
        p[i]  = __log2f(__fadd_rn(1.0f, __expf(-fabsf(fresh[i]))));
      }
      float T = (t3[0] + t3[1]) + (t3[2] + t3[3]);
      float P = (p[0]  + p[1])  + (p[2]  + p[3]);
      float F = fast_sum256(__builtin_fmaf(LN2F, P, T));   // fresh-side CE sum
      float sgn = nd ? 1.0f : -1.0f;
      float z = __builtin_fmaf(F - S_c, sgn, plj);         // ~ pl + lp1 - lp0
      float d = z - luj;                                   // NaN luj -> exact
      bool nw;
      if (__builtin_expect(!(fabsf(d) >= ZBAND), 0)) {
        // near-boundary: recompute BOTH sides with the bitwise numpy replica
        float one_m = __fsub_rn(1.0f, node);
        float nl0[4], nl1[4], c0i[4], c1i[4];
        #pragma unroll
        for (int i = 0; i < 4; ++i) {
          nl0[i] = __fsub_rn(nlv[i], __fmul_rn(node,  wv[i]));
          nl1[i] = __fadd_rn(nlv[i], __fmul_rn(one_m, wv[i]));
          c0i[i] = ce32(nl0[i], nv[i], tab);
          c1i[i] = ce32(nl1[i], nv[i], tab);
        }
        float S0e = fold256_lds(c0i, scrw, idx, g);
        float S1e = fold256_lds(c1i, scrw, idx, g);
        float ze  = __fsub_rn(__fadd_rn(plj, -S1e), -S0e);
        nw  = decide(uj, np_expf(-ze));
        S_c = nw ? S1e : S0e;                     // re-anchor carry to exact
        #pragma unroll
        for (int i = 0; i < 4; ++i) nlv[i] = nw ? nl1[i] : nl0[i];
      } else {
        nw = d > 0.0f;                            // provably == reference
        bool flip = (nw != nd);
        S_c = flip ? F : S_c;
        #pragma unroll
        for (int i = 0; i < 4; ++i) nlv[i] = flip ? fresh[i] : nlv[i];
      }
      if (lane == 0) sm.h1n[wid][j] = nw ? 1.0f : 0.0f;
      supC = supN;
      #pragma unroll
      for (int i = 0; i < 4; ++i) wv[i] = wn[i];
    }
  }
  // h1n wave-private; no barrier needed

  // ---- phase 3: pl2 = h1_new @ W2 + b2 (branchless fma); repack staging ---
  {
    float acc[4] = {0.0f, 0.0f, 0.0f, 0.0f};
    for (int j = 0; j < HN; ++j) {
      float nodej = sm.h1n[wid][j];
      float4 wf = *reinterpret_cast<const float4*>(W2 + (size_t)j * HN + 4*lane);
      acc[0] = __builtin_fmaf(nodej, wf.x, acc[0]);
      acc[1] = __builtin_fmaf(nodej, wf.y, acc[1]);
      acc[2] = __builtin_fmaf(nodej, wf.z, acc[2]);
      acc[3] = __builtin_fmaf(nodej, wf.w, acc[3]);
    }
    float4 bv = *reinterpret_cast<const float4*>(b2 + 4*lane);
    float p2[4] = {__fadd_rn(acc[0], bv.x), __fadd_rn(acc[1], bv.y),
                   __fadd_rn(acc[2], bv.z), __fadd_rn(acc[3], bv.w)};
    #pragma unroll
    for (int i = 0; i < 4; ++i) {
      int j = 4 * lane + i;
      float u2v = u2[(size_t)j * NB + b];
      sm.sup[wid][j] = make_float4(sm.h2o[wid][j], u2v, p2[i], lu_of(u2v));
    }
  }

  // layer-1 init: nlo = h2_old @ Wout + bout (branchless fma); nvy = y
  float nvy = 0.0f, nlo = 0.0f;
  if (lane < NOUT) {
    nvy = sm.yv[wid][lane];
    float a = 0.0f;
    for (int j = 0; j < HN; ++j)
      a = __builtin_fmaf(sm.h2o[wid][j], Wo[j * NOUT + lane], a);
    nlo = __fadd_rn(a, bo[lane]);
  }
  float S_c1 = sum10((lane < NOUT) ? ce32(nlo, nvy, tab) : 0.0f);   // exact init
  const int  syk  = (nvy != 0.0f) ? (int)0x80000000 : 0;
  const bool lact = (lane < NOUT);

  // ---- phase 4: layer-1 scan (10 children on lanes 0..9) ------------------
  {
    float w = lact ? Wo[lane] : 0.0f;
    float4 supC = sm.sup[wid][0];
    for (int j = 0; j < HN; ++j) {
      float node = supC.x, uj = supC.y, plj = supC.z, luj = supC.w;
      bool  nd   = (node != 0.0f);
      int   jn   = (j + 1) & (HN - 1);
      float4 supN = sm.sup[wid][jn];
      float wnn = lact ? Wo[jn * NOUT + lane] : 0.0f;
      int ndm = nd ? (int)0x80000000 : 0;
      float ws = __int_as_float(__float_as_int(w) ^ ndm);
      float fresh = __fadd_rn(nlo, ws);
      float sl = __int_as_float(__float_as_int(fresh) ^ syk);
      float t3 = fmaxf(sl, 0.0f);
      float p  = __log2f(__fadd_rn(1.0f, __expf(-fabsf(fresh))));
      float loc = lact ? __builtin_fmaf(LN2F, p, t3) : 0.0f;
      float r = loc;
      r = r + dppx<0xB1>(r);
      r = r + dppx<0x4E>(r);
      float F  = (rdl(r, 0) + rdl(r, 4)) + rdl(r, 8);   // lanes 10..15 hold 0
      float sgn = nd ? 1.0f : -1.0f;
      float z = __builtin_fmaf(F - S_c1, sgn, plj);
      float d = z - luj;
      bool nw;
      if (__builtin_expect(!(fabsf(d) >= ZBAND), 0)) {
        float one_m = __fsub_rn(1.0f, node);
        float nl0 = __fsub_rn(nlo, __fmul_rn(node,  w));
        float nl1 = __fadd_rn(nlo, __fmul_rn(one_m, w));
        float c0 = lact ? ce32(nl0, nvy, tab) : 0.0f;
        float c1 = lact ? ce32(nl1, nvy, tab) : 0.0f;
        float S0e = sum10(c0);
        float S1e = sum10(c1);
        float ze  = __fsub_rn(__fadd_rn(plj, -S1e), -S0e);
        nw   = decide(uj, np_expf(-ze));
        S_c1 = nw ? S1e : S0e;
        nlo  = nw ? nl1 : nl0;
      } else {
        nw = d > 0.0f;
        bool flip = (nw != nd);
        S_c1 = flip ? F : S_c1;
        nlo  = flip ? fresh : nlo;
      }
      if (lane == 0) out[(size_t)b * OSTR + HN + j] = nw ? 1.0f : 0.0f;
      supC = supN;
      w = wnn;
    }
  }

  // ---- phase 5: outputs ---------------------------------------------------
  float* orow = out + (size_t)b * OSTR;
  for (int j = lane; j < HN; j += 64) orow[j] = sm.h1n[wid][j];
  if (lane < NOUT) orow[2*HN + lane] = nlo;
}

extern "C" void kernel_launch(void* const* d_in, const int* in_sizes, int n_in,
                              void* d_out, int out_size, void* d_ws, size_t ws_size,
                              hipStream_t stream) {
  const float* x  = (const float*)d_in[0];
  const int*   h1 = (const int*)  d_in[1];
  const int*   h2 = (const int*)  d_in[2];
  const int*   y  = (const int*)  d_in[3];
  const float* W1 = (const float*)d_in[4];
  const float* b1 = (const float*)d_in[5];
  const float* W2 = (const float*)d_in[6];
  const float* b2 = (const float*)d_in[7];
  const float* Wo = (const float*)d_in[8];
  const float* bo = (const float*)d_in[9];
  const float* u1 = (const float*)d_in[10];
  const float* u2 = (const float*)d_in[11];
  stoch_mlp<<<NB/4, 256, 0, stream>>>(x, h1, h2, y, W1, b1, W2, b2, Wo, bo, u1, u2,
                                      (float*)d_out);
}

// Round 4
// 318.502 us; speedup vs baseline: 1.8151x; 1.0188x over previous
//
#include <hip/hip_runtime.h>
#include <math.h>

#define NB   2048
#define DIN  784
#define HN   256
#define NOUT 10
#define OSTR (HN + HN + NOUT)   // 522

// Per-block LDS. sup/tab/scr are 16B-aligned by placement order.
struct Smem {
  float4  sup[4][HN];      // 16 KB: (node, u, parent-logit, logit(u) or NaN) per j
  double2 tab[65];         // 1040 B: {ln(k/64), 64/k}, k=64..128 (device-built)
  float   scr[4][16 * 20]; // 5 KB fold scratch (exact init + rare fallback only)
  float   h2o[4][HN];      // 4 KB
  float   h1n[4][HN];      // 4 KB
  float   tmp[4][HN];      // 4 KB nl-init redistribution
  float   yv [4][16];
};

// ---- bitwise replica of numpy's SIMD float32 exp (exact/fallback path) -----
__device__ __forceinline__ float np_expf(float xf) {
  float q = __fmul_rn(xf, 1.442695040888963f);       // x * NPY_LOG2Ef
  q = __fadd_rn(q, 12582912.0f);                     // 0x1.8p23 round-to-even
  q = __fsub_rn(q, 12582912.0f);
  float x = __builtin_fmaf(q, -6.93145752e-1f, xf);  // Cody-Waite high
  x = __builtin_fmaf(q, -1.42860677e-6f, x);         // Cody-Waite low
  float num = __builtin_fmaf(x, 5.082762527590693718096e-04f,
                                6.757896990527504603057e-03f);
  num = __builtin_fmaf(num, x, 5.114512081637298353406e-02f);
  num = __builtin_fmaf(num, x, 2.473615434895520810817e-01f);
  num = __builtin_fmaf(num, x, 7.257664613233124478488e-01f);
  num = __builtin_fmaf(num, x, 9.999999999980870924916e-01f);
  float den = __builtin_fmaf(x, 2.159509375685829852307e-02f,
                                -2.742335390411667452936e-01f);
  den = __builtin_fmaf(den, x, 1.0f);
  float r = __fdiv_rn(num, den);
  int qi = (int)q;
  return __fmul_rn(r, __int_as_float((qi + 127) << 23));
}

// fp64 log1p for e in (0,1] — bitwise replica class (exact/fallback path)
__device__ __forceinline__ float np_log1pf(float ef, const double2* __restrict__ tab) {
  if (ef < 0x1p-29f) return ef;            // never taken in practice
  double t  = 1.0 + (double)ef;            // exact
  double kd = rint(t * 64.0);              // k in [64, 128]
  int   idx = (int)kd - 64;
  double2 te = tab[idx];                   // {ln(c), 64/k} in one ds_read_b128
  double c  = kd * 0.015625;               // exact
  double s  = (t - c) * te.y;
  double p  = fma(s, -1.0/6.0, 0.2);
  p = fma(p, s, -0.25);
  p = fma(p, s,  1.0/3.0);
  p = fma(p, s, -0.5);
  p = fma(p, s,  1.0);
  p = p * s;                               // ln(1+s)
  return (float)(te.x + p);
}

// sigmoid-CE, numpy op order: (max(l,0) - l*label) + log1p(exp(-|l|))  [exact]
__device__ __forceinline__ float ce32(float l, float label, const double2* __restrict__ tab) {
  float t3 = __fsub_rn(fmaxf(l, 0.0f), __fmul_rn(l, label));
  return __fadd_rn(t3, np_log1pf(np_expf(-fabsf(l)), tab));
}

// Exact decision u < prob, prob = fl(1 / fl(1+exp(-z))) — divide-free w/ replica
// fallback within |d|<1e-5 of the boundary.  [exact/fallback path]
__device__ __forceinline__ bool decide(float u, float ez) {
  float w = __fadd_rn(1.0f, ez);
  float d = __builtin_fmaf(u, w, -1.0f);
  if (__builtin_expect(fabsf(d) < 1e-5f, 0)) {
    float prob = __fdiv_rn(1.0f, w);
    return u < prob;
  }
  return d < 0.0f;
}

// lane data movement (bitwise-safe)
template<int CTRL> __device__ __forceinline__ float dppx(float v) {
  return __int_as_float(__builtin_amdgcn_mov_dpp(__float_as_int(v), CTRL, 0xF, 0xF, true));
}
__device__ __forceinline__ float rdl(float v, int l) {
  return __int_as_float(__builtin_amdgcn_readlane(__float_as_int(v), l));
}

// numpy pairwise sum over 10 on lanes 0..9 (uniform result)  [exact/fallback]
__device__ __forceinline__ float sum10(float c) {
  float c0 = rdl(c, 0), c1 = rdl(c, 1), c2 = rdl(c, 2), c3 = rdl(c, 3);
  float c4 = rdl(c, 4), c5 = rdl(c, 5), c6 = rdl(c, 6), c7 = rdl(c, 7);
  float c8 = rdl(c, 8), c9 = rdl(c, 9);
  float t = __fadd_rn(__fadd_rn(__fadd_rn(c0, c1), __fadd_rn(c2, c3)),
                      __fadd_rn(__fadd_rn(c4, c5), __fadd_rn(c6, c7)));
  t = __fadd_rn(t, c8);
  t = __fadd_rn(t, c9);
  return t;
}

// numpy pairwise sum over 256 children (4/lane) via LDS scratch transpose.
// [exact — only used for init and the rare near-boundary fallback]
__device__ __forceinline__ float fold256_lds(const float c[4], float* __restrict__ scrw,
                                             int idx, int g) {
  *reinterpret_cast<float4*>(scrw + idx * 20 + 4 * g) = make_float4(c[0], c[1], c[2], c[3]);
  const float4* rp = reinterpret_cast<const float4*>(scrw + idx * 20);
  float4 q0 = rp[0], q1 = rp[1], q2 = rp[2], q3 = rp[3];
  float r = q0.x;
  r = __fadd_rn(r, q0.y); r = __fadd_rn(r, q0.z); r = __fadd_rn(r, q0.w);
  r = __fadd_rn(r, q1.x); r = __fadd_rn(r, q1.y); r = __fadd_rn(r, q1.z); r = __fadd_rn(r, q1.w);
  r = __fadd_rn(r, q2.x); r = __fadd_rn(r, q2.y); r = __fadd_rn(r, q2.z); r = __fadd_rn(r, q2.w);
  r = __fadd_rn(r, q3.x); r = __fadd_rn(r, q3.y); r = __fadd_rn(r, q3.z); r = __fadd_rn(r, q3.w);
  r = __fadd_rn(r, dppx<0xB1>(r));      // xor 1 (quad_perm [1,0,3,2])
  r = __fadd_rn(r, dppx<0x4E>(r));      // xor 2 (quad_perm [2,3,0,1])
  float B0 = rdl(r, 0), B1 = rdl(r, 4), B2 = rdl(r, 8), B3 = rdl(r, 12);
  return __fadd_rn(__fadd_rn(B0, B1), __fadd_rn(B2, B3));
}

// ---- FAST path helpers ------------------------------------------------------
// fast 256-sum, all-DPP: quad ^1, ^2, row_ror:4, row_ror:8 give every lane its
// 16-row sum; row_bcast15 + row_bcast31 accumulate rows into lane 63; a single
// readlane makes F exactly wave-uniform (keeps the decision branch uniform).
// Any deterministic summation order is covered by the ZBAND error budget.
__device__ __forceinline__ float fast_sum256(float loc) {
  float r = loc;
  r = r + dppx<0xB1>(r);                  // quad xor 1
  r = r + dppx<0x4E>(r);                  // quad xor 2
  r = r + dppx<0x124>(r);                 // row_ror:4
  r = r + dppx<0x128>(r);                 // row_ror:8  -> row sums everywhere
  r = r + dppx<0x142>(r);                 // row_bcast15
  r = r + dppx<0x143>(r);                 // row_bcast31 -> lane63 = total
  return rdl(r, 63);
}

// Precomputed decision threshold in z-space: u < sigmoid_fl(z)  <=>  z > lu,
// valid outside a |z-lu| < 0.05 band for u in [1e-4, 0.9999] (fast-sum error
// <=~3e-3 + fl-sigmoid boundary offset <=~2e-3 at the cutoff -> >=10x margin).
// Extreme u -> NaN, which routes !(|d|>=thr) to the exact path.
__device__ __forceinline__ float lu_of(float u) {
  if (u < 1e-4f || u > 0.9999f) return __int_as_float(0x7FC00000);
  return __logf(u) - __logf(__fsub_rn(1.0f, u));
}

#define ZBAND 0.05f
#define LN2F  0.6931471805599453f

__global__ __launch_bounds__(256) void stoch_mlp(
    const float* __restrict__ x,  const int* __restrict__ h1,
    const int* __restrict__ h2,   const int* __restrict__ y,
    const float* __restrict__ W1, const float* __restrict__ b1,
    const float* __restrict__ W2, const float* __restrict__ b2,
    const float* __restrict__ Wo, const float* __restrict__ bo,
    const float* __restrict__ u1, const float* __restrict__ u2,
    float* __restrict__ out)
{
  __shared__ Smem sm;
  const int t    = threadIdx.x;
  const int lane = t & 63;
  const int wid  = t >> 6;            // wave id == local batch row
  const int b0   = blockIdx.x * 4;
  const int b    = b0 + wid;

  // ---- phase 1: tables, states, pl1 = x@W1 (BLAS fp32) + packed staging ---
  if (t < 65) {
    double c = (double)(t + 64) * 0.015625;
    sm.tab[t] = make_double2(log(c), 64.0 / (double)(t + 64));
  }
  for (int j = lane; j < HN; j += 64) sm.h2o[wid][j] = (float)h2[b * HN + j];
  if (lane < 16) sm.yv[wid][lane] = (lane < NOUT) ? (float)y[b * NOUT + lane] : 0.0f;
  {
    float a0 = 0.0f, a1 = 0.0f, a2 = 0.0f, a3 = 0.0f;   // sequential-k FMA chains
    const float* x0 = x + (size_t)b0 * DIN;
    // 2-deep prefetch of the W1 row stream (order of FMA chain unchanged)
    float wk0 = W1[t];
    float wk1 = W1[HN + t];
    for (int k = 0; k < DIN; ++k) {
      int k2 = (k + 2 < DIN) ? (k + 2) : 0;
      float wk2 = W1[(size_t)k2 * HN + t];
      a0 = __builtin_fmaf(x0[k],           wk0, a0);
      a1 = __builtin_fmaf(x0[DIN   + k],   wk0, a1);
      a2 = __builtin_fmaf(x0[2*DIN + k],   wk0, a2);
      a3 = __builtin_fmaf(x0[3*DIN + k],   wk0, a3);
      wk0 = wk1; wk1 = wk2;
    }
    float bb = b1[t];
    float4 uv = *reinterpret_cast<const float4*>(u1 + (size_t)t * NB + b0);
    float n0 = (float)h1[(b0 + 0) * HN + t];
    float n1 = (float)h1[(b0 + 1) * HN + t];
    float n2 = (float)h1[(b0 + 2) * HN + t];
    float n3 = (float)h1[(b0 + 3) * HN + t];
    sm.sup[0][t] = make_float4(n0, uv.x, __fadd_rn(a0, bb), lu_of(uv.x));
    sm.sup[1][t] = make_float4(n1, uv.y, __fadd_rn(a1, bb), lu_of(uv.y));
    sm.sup[2][t] = make_float4(n2, uv.z, __fadd_rn(a2, bb), lu_of(uv.z));
    sm.sup[3][t] = make_float4(n3, uv.w, __fadd_rn(a3, bb), lu_of(uv.w));
  }
  __syncthreads();   // sup + tab written cross-wave

  const double2* tab = sm.tab;
  float* scrw = &sm.scr[wid][0];

  // nl-init = h1_old @ W2 + b2. Branchless fma(node,w,acc) is bitwise == the
  // masked add chain: fma(1,w,a)=fl(w+a), fma(0,w,a)=a (acc never -0).
  {
    float acc[4] = {0.0f, 0.0f, 0.0f, 0.0f};
    for (int j = 0; j < HN; ++j) {
      float nodej = sm.sup[wid][j].x;
      float4 wf = *reinterpret_cast<const float4*>(W2 + (size_t)j * HN + 4*lane);
      acc[0] = __builtin_fmaf(nodej, wf.x, acc[0]);
      acc[1] = __builtin_fmaf(nodej, wf.y, acc[1]);
      acc[2] = __builtin_fmaf(nodej, wf.z, acc[2]);
      acc[3] = __builtin_fmaf(nodej, wf.w, acc[3]);
    }
    float4 bv = *reinterpret_cast<const float4*>(b2 + 4*lane);
    *reinterpret_cast<float4*>(&sm.tmp[wid][4*lane]) =
        make_float4(__fadd_rn(acc[0], bv.x), __fadd_rn(acc[1], bv.y),
                    __fadd_rn(acc[2], bv.z), __fadd_rn(acc[3], bv.w));
  }
  // tmp is wave-private; same-wave DS ordering -> no barrier

  // ---- phase 2: layer-0 scan — 4 children per lane ------------------------
  const int idx  = lane & 15;
  const int g    = lane >> 4;
  const int half = idx >> 3;
  const int jacc = idx & 7;
  const int kb   = half * 128 + (4 * g) * 8 + jacc;   // + i*8

  float nlv[4], nv[4];
  int   smk[4];                        // per-child label sign mask
  #pragma unroll
  for (int i = 0; i < 4; ++i) {
    int k = kb + i * 8;
    nlv[i] = sm.tmp[wid][k];
    nv[i]  = sm.h2o[wid][k];
    smk[i] = (nv[i] != 0.0f) ? (int)0x80000000 : 0;
  }
  float S_c;                           // carried CE sum (fast between fallbacks)
  {
    float ci[4];                       // exact init (once): tight anchor
    #pragma unroll
    for (int i = 0; i < 4; ++i) ci[i] = ce32(nlv[i], nv[i], tab);
    S_c = fold256_lds(ci, scrw, idx, g);
  }

  {
    // 2-deep prefetch: sup rows j, j+1 and W2 rows j, j+1 resident; j+2 issued
    float4 supC = sm.sup[wid][0];
    float4 supN = sm.sup[wid][1];
    float w0[4], w1[4];
    #pragma unroll
    for (int i = 0; i < 4; ++i) {
      w0[i] = W2[kb + i * 8];                      // row 0
      w1[i] = W2[(size_t)HN + kb + i * 8];         // row 1
    }
    #pragma unroll 2
    for (int j = 0; j < HN; ++j) {
      int jn2 = (j + 2) & (HN - 1);                // wrapped prefetch (harmless reload)
      float4 supN2 = sm.sup[wid][jn2];
      float wp[4];
      #pragma unroll
      for (int i = 0; i < 4; ++i) wp[i] = W2[(size_t)jn2 * HN + kb + i * 8];

      float node = supC.x, uj = supC.y, plj = supC.z, luj = supC.w;
      bool  nd   = (node != 0.0f);
      // fresh side only: the stale side is bitwise nlv itself (node in {0,1})
      int ndm = nd ? (int)0x80000000 : 0;
      float fresh[4], t3[4], p[4];
      #pragma unroll
      for (int i = 0; i < 4; ++i) {
        float ws = __int_as_float(__float_as_int(w0[i]) ^ ndm);  // exact +/-w
        fresh[i] = __fadd_rn(nlv[i], ws);        // == fl(nlv -/+ w) bitwise
        float sl = __int_as_float(__float_as_int(fresh[i]) ^ smk[i]);
        t3[i] = fmaxf(sl, 0.0f);                 // == max(l,0)-l*label bitwise
        p[i]  = __log2f(__fadd_rn(1.0f, __expf(-fabsf(fresh[i]))));
      }
      float T = (t3[0] + t3[1]) + (t3[2] + t3[3]);
      float P = (p[0]  + p[1])  + (p[2]  + p[3]);
      float F = fast_sum256(__builtin_fmaf(LN2F, P, T));   // fresh-side CE sum
      float sgn = nd ? 1.0f : -1.0f;
      float z = __builtin_fmaf(F - S_c, sgn, plj);         // ~ pl + lp1 - lp0
      float d = z - luj;                                   // NaN luj -> exact
      bool nw;
      if (__builtin_expect(!(fabsf(d) >= ZBAND), 0)) {
        // near-boundary: recompute BOTH sides with the bitwise numpy replica
        float one_m = __fsub_rn(1.0f, node);
        float nl0[4], nl1[4], c0i[4], c1i[4];
        #pragma unroll
        for (int i = 0; i < 4; ++i) {
          nl0[i] = __fsub_rn(nlv[i], __fmul_rn(node,  w0[i]));
          nl1[i] = __fadd_rn(nlv[i], __fmul_rn(one_m, w0[i]));
          c0i[i] = ce32(nl0[i], nv[i], tab);
          c1i[i] = ce32(nl1[i], nv[i], tab);
        }
        float S0e = fold256_lds(c0i, scrw, idx, g);
        float S1e = fold256_lds(c1i, scrw, idx, g);
        float ze  = __fsub_rn(__fadd_rn(plj, -S1e), -S0e);
        nw  = decide(uj, np_expf(-ze));
        S_c = nw ? S1e : S0e;                     // re-anchor carry to exact
        #pragma unroll
        for (int i = 0; i < 4; ++i) nlv[i] = nw ? nl1[i] : nl0[i];
      } else {
        nw = d > 0.0f;                            // provably == reference
        bool flip = (nw != nd);
        S_c = flip ? F : S_c;
        #pragma unroll
        for (int i = 0; i < 4; ++i) nlv[i] = flip ? fresh[i] : nlv[i];
      }
      if (lane == 0) sm.h1n[wid][j] = nw ? 1.0f : 0.0f;
      supC = supN; supN = supN2;
      #pragma unroll
      for (int i = 0; i < 4; ++i) { w0[i] = w1[i]; w1[i] = wp[i]; }
    }
  }
  // h1n wave-private; no barrier needed

  // ---- phase 3: pl2 = h1_new @ W2 + b2 (branchless fma); repack staging ---
  {
    float acc[4] = {0.0f, 0.0f, 0.0f, 0.0f};
    for (int j = 0; j < HN; ++j) {
      float nodej = sm.h1n[wid][j];
      float4 wf = *reinterpret_cast<const float4*>(W2 + (size_t)j * HN + 4*lane);
      acc[0] = __builtin_fmaf(nodej, wf.x, acc[0]);
      acc[1] = __builtin_fmaf(nodej, wf.y, acc[1]);
      acc[2] = __builtin_fmaf(nodej, wf.z, acc[2]);
      acc[3] = __builtin_fmaf(nodej, wf.w, acc[3]);
    }
    float4 bv = *reinterpret_cast<const float4*>(b2 + 4*lane);
    float p2[4] = {__fadd_rn(acc[0], bv.x), __fadd_rn(acc[1], bv.y),
                   __fadd_rn(acc[2], bv.z), __fadd_rn(acc[3], bv.w)};
    #pragma unroll
    for (int i = 0; i < 4; ++i) {
      int j = 4 * lane + i;
      float u2v = u2[(size_t)j * NB + b];
      sm.sup[wid][j] = make_float4(sm.h2o[wid][j], u2v, p2[i], lu_of(u2v));
    }
  }

  // layer-1 init: nlo = h2_old @ Wout + bout (branchless fma); nvy = y
  float nvy = 0.0f, nlo = 0.0f;
  if (lane < NOUT) {
    nvy = sm.yv[wid][lane];
    float a = 0.0f;
    for (int j = 0; j < HN; ++j)
      a = __builtin_fmaf(sm.h2o[wid][j], Wo[j * NOUT + lane], a);
    nlo = __fadd_rn(a, bo[lane]);
  }
  float S_c1 = sum10((lane < NOUT) ? ce32(nlo, nvy, tab) : 0.0f);   // exact init
  const int  syk  = (nvy != 0.0f) ? (int)0x80000000 : 0;
  const bool lact = (lane < NOUT);

  // ---- phase 4: layer-1 scan (10 children on lanes 0..9) ------------------
  {
    float4 supC = sm.sup[wid][0];
    float4 supN = sm.sup[wid][1];
    float w0s = lact ? Wo[lane] : 0.0f;
    float w1s = lact ? Wo[NOUT + lane] : 0.0f;
    #pragma unroll 2
    for (int j = 0; j < HN; ++j) {
      int jn2 = (j + 2) & (HN - 1);
      float4 supN2 = sm.sup[wid][jn2];
      float wps = lact ? Wo[jn2 * NOUT + lane] : 0.0f;

      float node = supC.x, uj = supC.y, plj = supC.z, luj = supC.w;
      bool  nd   = (node != 0.0f);
      int ndm = nd ? (int)0x80000000 : 0;
      float ws = __int_as_float(__float_as_int(w0s) ^ ndm);
      float fresh = __fadd_rn(nlo, ws);
      float sl = __int_as_float(__float_as_int(fresh) ^ syk);
      float t3 = fmaxf(sl, 0.0f);
      float p  = __log2f(__fadd_rn(1.0f, __expf(-fabsf(fresh))));
      float loc = lact ? __builtin_fmaf(LN2F, p, t3) : 0.0f;
      // fast 10-sum: ^1, ^2, ror4, ror8 -> lane0 holds full sum; 1 readlane
      float r = loc;
      r = r + dppx<0xB1>(r);
      r = r + dppx<0x4E>(r);
      r = r + dppx<0x124>(r);
      r = r + dppx<0x128>(r);
      float F  = rdl(r, 0);
      float sgn = nd ? 1.0f : -1.0f;
      float z = __builtin_fmaf(F - S_c1, sgn, plj);
      float d = z - luj;
      bool nw;
      if (__builtin_expect(!(fabsf(d) >= ZBAND), 0)) {
        float one_m = __fsub_rn(1.0f, node);
        float nl0 = __fsub_rn(nlo, __fmul_rn(node,  w0s));
        float nl1 = __fadd_rn(nlo, __fmul_rn(one_m, w0s));
        float c0 = lact ? ce32(nl0, nvy, tab) : 0.0f;
        float c1 = lact ? ce32(nl1, nvy, tab) : 0.0f;
        float S0e = sum10(c0);
        float S1e = sum10(c1);
        float ze  = __fsub_rn(__fadd_rn(plj, -S1e), -S0e);
        nw   = decide(uj, np_expf(-ze));
        S_c1 = nw ? S1e : S0e;
        nlo  = nw ? nl1 : nl0;
      } else {
        nw = d > 0.0f;
        bool flip = (nw != nd);
        S_c1 = flip ? F : S_c1;
        nlo  = flip ? fresh : nlo;
      }
      if (lane == 0) out[(size_t)b * OSTR + HN + j] = nw ? 1.0f : 0.0f;
      supC = supN; supN = supN2;
      w0s = w1s; w1s = wps;
    }
  }

  // ---- phase 5: outputs ---------------------------------------------------
  float* orow = out + (size_t)b * OSTR;
  for (int j = lane; j < HN; j += 64) orow[j] = sm.h1n[wid][j];
  if (lane < NOUT) orow[2*HN + lane] = nlo;
}

extern "C" void kernel_launch(void* const* d_in, const int* in_sizes, int n_in,
                              void* d_out, int out_size, void* d_ws, size_t ws_size,
                              hipStream_t stream) {
  const float* x  = (const float*)d_in[0];
  const int*   h1 = (const int*)  d_in[1];
  const int*   h2 = (const int*)  d_in[2];
  const int*   y  = (const int*)  d_in[3];
  const float* W1 = (const float*)d_in[4];
  const float* b1 = (const float*)d_in[5];
  const float* W2 = (const float*)d_in[6];
  const float* b2 = (const float*)d_in[7];
  const float* Wo = (const float*)d_in[8];
  const float* bo = (const float*)d_in[9];
  const float* u1 = (const float*)d_in[10];
  const float* u2 = (const float*)d_in[11];
  stoch_mlp<<<NB/4, 256, 0, stream>>>(x, h1, h2, y, W1, b1, W2, b2, Wo, bo, u1, u2,
                                      (float*)d_out);
}